// Round 3
// baseline (524.993 us; speedup 1.0000x reference)
//
#include <hip/hip_runtime.h>
#include <hip/hip_bf16.h>

// ModulatedConv2d: B=16, Cin=Cout=512, H=W=64, 3x3, pad 1.
// out[b,o] = dscale[b,o] * conv2d(s[b,:]*x[b], weight)   (weights shared across batch)

constexpr float CONV_SCALE = 0.014731391274719738f;  // 1/sqrt(512*9)
constexpr float MOD_SCALE  = 0.04419417382415922f;   // 1/sqrt(512)

typedef short  bf16x8 __attribute__((ext_vector_type(8)));
typedef float  f32x4  __attribute__((ext_vector_type(4)));

__device__ __forceinline__ unsigned short f2bf(float f) {
  unsigned u = __float_as_uint(f);
  u += 0x7fffu + ((u >> 16) & 1u);           // round-to-nearest-even
  return (unsigned short)(u >> 16);
}

__device__ __forceinline__ void async16(const void* g, void* l) {
  __builtin_amdgcn_global_load_lds((const __attribute__((address_space(1))) unsigned int*)g,
                                   (__attribute__((address_space(3))) unsigned int*)l,
                                   16, 0, 0);
}

// ---------- kernel 1: s[b,i] = style[b,:] . mod_weight[i,:] * MOD_SCALE + mod_bias[i] ----------
__global__ void k_style(const float* __restrict__ style, const float* __restrict__ mw,
                        const float* __restrict__ mb, float* __restrict__ s) {
  int t = blockIdx.x * 256 + threadIdx.x;    // 8192 threads
  int b = t & 15, i = t >> 4;
  const float4* st = (const float4*)(style + b * 512);
  const float4* wr = (const float4*)(mw + i * 512);
  float acc = 0.f;
#pragma unroll 8
  for (int j = 0; j < 128; ++j) {
    float4 a = st[j], w4 = wr[j];
    acc += a.x * w4.x + a.y * w4.y + a.z * w4.z + a.w * w4.w;
  }
  s[b * 512 + i] = acc * MOD_SCALE + mb[i];
}

// ---------- kernel 2: wsq[o,i] = sum_taps w^2 ; wt[kh][kw][o][ic] = bf16(w) ----------
__global__ void k_prepw(const float* __restrict__ w, float* __restrict__ wsq,
                        unsigned short* __restrict__ wt) {
  __shared__ float Wl[2304];
  int t = threadIdx.x;
  size_t base = (size_t)blockIdx.x * 2304;
#pragma unroll
  for (int k = 0; k < 3; ++k) {
    int idx = t + k * 256;
    if (idx < 576) ((float4*)Wl)[idx] = ((const float4*)(w + base))[idx];
  }
  __syncthreads();
  int g = blockIdx.x * 256 + t;
  int ic = g & 511, o = g >> 9;
  float ssq = 0.f;
#pragma unroll
  for (int tap = 0; tap < 9; ++tap) {
    float v = Wl[t * 9 + tap];
    ssq += v * v;
    wt[((size_t)tap * 512 + o) * 512 + ic] = f2bf(v);
  }
  wsq[o * 512 + ic] = ssq;
}

// ---------- kernel 3: dscale[b,o] = rsqrt(CS^2 * sum_i wsq[o,i]*s[b,i]^2 + 1e-8) * CS ----------
__global__ void k_dscale(const float* __restrict__ s, const float* __restrict__ wsq,
                         float* __restrict__ dscale) {
  int t = blockIdx.x * 256 + threadIdx.x;    // 8192 threads
  int b = t & 15, o = t >> 4;
  const float4* sq = (const float4*)(wsq + o * 512);
  const float4* sb = (const float4*)(s + b * 512);
  float acc = 0.f;
#pragma unroll 8
  for (int j = 0; j < 128; ++j) {
    float4 q4 = sq[j], s4 = sb[j];
    acc += q4.x * s4.x * s4.x + q4.y * s4.y * s4.y + q4.z * s4.z * s4.z + q4.w * s4.w * s4.w;
  }
  float d = rsqrtf(CONV_SCALE * CONV_SCALE * acc + 1e-8f);
  dscale[b * 512 + o] = d * CONV_SCALE;
}

// ---------- kernel 4: xt[b][h][w][ic] = bf16(x[b][ic][h][w] * s[b][ic])  (NCHW->NHWC) ----------
// T padded to 65 floats/row: 65 = 1 mod 32 -> both phases conflict-free (68 was 8-way on reads).
__global__ void k_xt(const float* __restrict__ x, const float* __restrict__ s,
                     unsigned short* __restrict__ xt) {
  __shared__ float T[64][65];
  int h = blockIdx.x, b = blockIdx.y;
  const float* xp = x + (size_t)b * 512 * 4096 + h * 64;
  unsigned short* xo = xt + ((size_t)(b * 64 + h) * 64) * 512;
  int t = threadIdx.x;
  for (int ic0 = 0; ic0 < 512; ic0 += 64) {
    // load 64 ic-rows x 64 w as float4 (coalesced 16B/lane), scale, scalar-write to padded T
#pragma unroll
    for (int k = 0; k < 4; ++k) {
      int idx = t + k * 256;          // 1024 float4s
      int icl = idx >> 4, cc = (idx & 15) * 4;
      int ic = ic0 + icl;
      float4 v = *(const float4*)&xp[(size_t)ic * 4096 + cc];
      float sc = s[b * 512 + ic];
      T[icl][cc + 0] = v.x * sc;
      T[icl][cc + 1] = v.y * sc;
      T[icl][cc + 2] = v.z * sc;
      T[icl][cc + 3] = v.w * sc;
    }
    __syncthreads();
    // transpose out: [w][ic] with 8-ch bf16 packs
#pragma unroll
    for (int c = t; c < 512; c += 256) {   // 64 w * 8 groups of 8 ch
      int wv = c >> 3, ig = (c & 7) * 8;
      unsigned p0 = (unsigned)f2bf(T[ig + 0][wv]) | ((unsigned)f2bf(T[ig + 1][wv]) << 16);
      unsigned p1 = (unsigned)f2bf(T[ig + 2][wv]) | ((unsigned)f2bf(T[ig + 3][wv]) << 16);
      unsigned p2 = (unsigned)f2bf(T[ig + 4][wv]) | ((unsigned)f2bf(T[ig + 5][wv]) << 16);
      unsigned p3 = (unsigned)f2bf(T[ig + 6][wv]) | ((unsigned)f2bf(T[ig + 7][wv]) << 16);
      uint4 pk = {p0, p1, p2, p3};
      *(uint4*)&xo[(size_t)wv * 512 + ic0 + ig] = pk;
    }
    __syncthreads();
  }
}

// ---------- kernel 5: the conv (implicit GEMM, MFMA bf16, software-pipelined) ----------
// grid (16 h-tiles, 4 o-tiles, 16 b); block 256 = 4 waves.
// Tile: 128 o x (4 rows x 64 cols). Wave: 128 o x 1 row; 8x4 accs of 16x16.
// Pipeline: Ws double-buffered, W(s+1) issued BEFORE compute(s) so the barrier's
// vmcnt(0) drain hits already-complete loads. X prefetched to regs during kh=0,
// published via ds_write after kh=2 (extra barrier drains lgkm only).
// LDS = 25344 + 49152 = 74496 B -> 2 blocks/CU -> grid 1024 = two clean rounds of 512.
__global__ __launch_bounds__(256, 2)
void k_conv(const unsigned short* __restrict__ xt, const unsigned short* __restrict__ wt,
            const float* __restrict__ dscale, float* __restrict__ out) {
  __shared__ short Xs[6 * 66 * 32];        // [row(4+2 halo)][col(pad+64+pad)][ic32]
  __shared__ short Ws[2][3 * 128 * 32];    // [buf][kw][o128][ic32]

  const int b  = blockIdx.z;
  const int o0 = blockIdx.y * 128;
  const int h0 = blockIdx.x * 4;
  const int t = threadIdx.x;
  const int wave = t >> 6, lane = t & 63;
  const int q = lane >> 4, l16 = lane & 15;

  f32x4 acc[8][4];
#pragma unroll
  for (int i = 0; i < 8; ++i)
#pragma unroll
    for (int j = 0; j < 4; ++j) acc[i][j] = (f32x4){0.f, 0.f, 0.f, 0.f};

  // zero the halo columns (col 0 and 65) of all 6 rows; never overwritten
  if (t < 192) {
    int r = t >> 5, rem = t & 31;
    int col = (rem >> 4) * 65, ch2 = (rem & 15) * 2;
    *(int*)&Xs[(r * 66 + col) * 32 + ch2] = 0;
  }

  // ---- X prefetch setup: thread t covers (col = t>>2, 8ch-quarter = t&3) for rows 0..5
  const int xcol = t >> 2, xq = t & 3;
  bool rv[6]; size_t xsrc[6]; int xlds[6];
#pragma unroll
  for (int j = 0; j < 6; ++j) {
    int hg = h0 - 1 + j;
    rv[j] = (hg >= 0) && (hg < 64);
    xsrc[j] = ((size_t)((b * 64 + (rv[j] ? hg : 0)) * 64 + xcol)) * 512 + xq * 8;
    xlds[j] = ((j * 66) + 1 + xcol) * 32 + xq * 8;
  }

  // ---- W staging setup: 24 chunks of 1KB per fill; 6 per wave
  size_t wsrc[6]; int wlds[6];
#pragma unroll
  for (int j = 0; j < 6; ++j) {
    int ci = wave * 6 + j;
    int kw = ci >> 3, oo = ((ci & 7) << 4) + (lane >> 2);
    wsrc[j] = ((size_t)(kw * 512 + o0 + oo)) * 512 + (lane & 3) * 8;  // + kh*786432 + ic0
    wlds[j] = ci * 512;
  }

  // ---- preamble: X(0) regs -> LDS; W(icb=0,kh=0) -> Ws[0]
  int4 xr[6];
#pragma unroll
  for (int j = 0; j < 6; ++j)
    xr[j] = rv[j] ? *(const int4*)(xt + xsrc[j]) : (int4){0, 0, 0, 0};
#pragma unroll
  for (int j = 0; j < 6; ++j)
    async16(wt + wsrc[j], &Ws[0][wlds[j]]);
#pragma unroll
  for (int j = 0; j < 6; ++j)
    *(int4*)&Xs[xlds[j]] = xr[j];
  __syncthreads();

  for (int icb = 0; icb < 16; ++icb) {
    const int ic0 = icb * 32;
#pragma unroll
    for (int kh = 0; kh < 3; ++kh) {
      // prefetch W for the next stage into the other buffer (hidden behind this compute)
      const bool last = (icb == 15) && (kh == 2);
      if (!last) {
        const int nkh = (kh < 2) ? kh + 1 : 0;
        const int nic = (kh < 2) ? ic0 : ic0 + 32;
        short* wb = Ws[(icb + kh + 1) & 1];
#pragma unroll
        for (int j = 0; j < 6; ++j)
          async16(wt + wsrc[j] + (size_t)nkh * 786432 + nic, &wb[wlds[j]]);
      }
      // prefetch next ic-block of X into registers (hidden behind kh=0 compute)
      if (kh == 0 && icb < 15) {
#pragma unroll
        for (int j = 0; j < 6; ++j)
          if (rv[j]) xr[j] = *(const int4*)(xt + xsrc[j] + ic0 + 32);
      }
      // ---- compute from Ws[(icb+kh)&1] and Xs
      const short* wsb = Ws[(icb + kh) & 1];
      const short* xbase = &Xs[(wave + kh) * 66 * 32 + q * 8];
#pragma unroll
      for (int kw = 0; kw < 3; ++kw) {
        bf16x8 bfr[4];
#pragma unroll
        for (int ni = 0; ni < 4; ++ni)
          bfr[ni] = *(const bf16x8*)&xbase[(ni * 16 + l16 + kw) * 32];
#pragma unroll
        for (int mi = 0; mi < 8; ++mi) {
          bf16x8 af = *(const bf16x8*)&wsb[(kw * 128 + mi * 16 + l16) * 32 + q * 8];
#pragma unroll
          for (int ni = 0; ni < 4; ++ni)
            acc[mi][ni] = __builtin_amdgcn_mfma_f32_16x16x32_bf16(af, bfr[ni], acc[mi][ni], 0, 0, 0);
        }
      }
      __syncthreads();
      // publish prefetched X for the next ic-block (lgkm-only barrier)
      if (kh == 2 && icb < 15) {
#pragma unroll
        for (int j = 0; j < 6; ++j)
          *(int4*)&Xs[xlds[j]] = xr[j];
        __syncthreads();
      }
    }
  }

  // ---- epilogue: D[row=q*4+r][col=l16] per 16x16 frag; scale by dscale[b,o]
  const int h = h0 + wave;
#pragma unroll
  for (int mi = 0; mi < 8; ++mi) {
#pragma unroll
    for (int r = 0; r < 4; ++r) {
      int o_l = mi * 16 + q * 4 + r;
      float ds = dscale[b * 512 + o0 + o_l];
      float* orow = out + ((size_t)(b * 512 + o0 + o_l) * 64 + h) * 64;
#pragma unroll
      for (int ni = 0; ni < 4; ++ni)
        orow[ni * 16 + l16] = acc[mi][ni][r] * ds;
    }
  }
}

extern "C" void kernel_launch(void* const* d_in, const int* in_sizes, int n_in,
                              void* d_out, int out_size, void* d_ws, size_t ws_size,
                              hipStream_t stream) {
  const float* x      = (const float*)d_in[0];  // (16,512,64,64)
  const float* style  = (const float*)d_in[1];  // (16,512)
  const float* weight = (const float*)d_in[2];  // (1,512,512,3,3)
  const float* mw     = (const float*)d_in[3];  // (512,512)
  const float* mb     = (const float*)d_in[4];  // (512,)
  float* out = (float*)d_out;

  // workspace layout
  float* s      = (float*)d_ws;                       // 8192 f32
  float* dscale = s + 8192;                           // 8192 f32
  float* wsq    = dscale + 8192;                      // 262144 f32
  unsigned short* wt = (unsigned short*)(wsq + 262144);  // 9*512*512 bf16 = 4.5 MiB
  unsigned short* xt = wt + 9 * 512 * 512;            // 16*64*64*512 bf16 = 64 MiB

  k_style<<<32, 256, 0, stream>>>(style, mw, mb, s);
  k_prepw<<<1024, 256, 0, stream>>>(weight, wsq, wt);
  k_dscale<<<32, 256, 0, stream>>>(s, wsq, dscale);
  k_xt<<<dim3(64, 16), 256, 0, stream>>>(x, s, xt);
  k_conv<<<dim3(16, 4, 16), 256, 0, stream>>>(xt, wt, dscale, out);
}